// Round 1
// baseline (312.341 us; speedup 1.0000x reference)
//
#include <hip/hip_runtime.h>

// Problem constants: B=8, N=2048, C=512, CR=64
#define PB 8
#define PN 2048
#define PC 512

typedef __attribute__((ext_vector_type(4))) float f32x4;
typedef __attribute__((ext_vector_type(8))) __bf16 bf16x8;
typedef __attribute__((ext_vector_type(8))) unsigned short u16x8;

__device__ __forceinline__ unsigned short f2bf(float f) {
  unsigned u = __builtin_bit_cast(unsigned, f);
  u += 0x7fffu + ((u >> 16) & 1u);
  return (unsigned short)(u >> 16);
}

__device__ __forceinline__ bf16x8 frag_at(const unsigned short* p) {
  return *reinterpret_cast<const bf16x8*>(p);
}

__device__ __forceinline__ f32x4 mfma16(bf16x8 a, bf16x8 b, f32x4 c) {
  return __builtin_amdgcn_mfma_f32_16x16x32_bf16(a, b, c, 0, 0, 0);
}

// ---------------- prep: cast weights to bf16, concat Wk/Wv ----------------
__global__ void prep_kernel(const float* __restrict__ Wk, const float* __restrict__ bk,
                            const float* __restrict__ Wv, const float* __restrict__ bv,
                            const float* __restrict__ Wq,
                            unsigned short* __restrict__ W1, float* __restrict__ b1,
                            unsigned short* __restrict__ Wqb) {
  int i = blockIdx.x * blockDim.x + threadIdx.x;
  int stride = gridDim.x * blockDim.x;
  for (int t = i; t < 128 * 512; t += stride) {
    int o = t >> 9, c = t & 511;
    float v = (o < 64) ? Wk[o * 512 + c] : Wv[(o - 64) * 512 + c];
    W1[t] = f2bf(v);
  }
  for (int t = i; t < 512 * 512; t += stride) Wqb[t] = f2bf(Wq[t]);
  if (i < 64) b1[i] = bk[i];
  else if (i < 128) b1[i] = bv[i - 64];
}

// ---------------- P1: k[b,n,64], vt[b,n,64] = x @ [Wk;Wv]^T + bias --------
// GEMM: M=16384 tokens, N'=128, K=512.  A=x rows (fp32->bf16), B=W1 rows.
__global__ __launch_bounds__(256) void proj_kv_kernel(
    const float* __restrict__ x, const unsigned short* __restrict__ W1,
    const float* __restrict__ b1,
    unsigned short* __restrict__ kbf, unsigned short* __restrict__ vtbf) {
  __shared__ unsigned short As[64][40];   // [token][k]  (+8 pad)
  __shared__ unsigned short Bs[128][40];  // [o][k]
  const int t = threadIdx.x;
  const int m0 = blockIdx.x * 64;
  const int w = t >> 6, lane = t & 63, lr = lane & 15, lg = lane >> 4;
  f32x4 acc[8];
#pragma unroll
  for (int i = 0; i < 8; ++i) acc[i] = (f32x4){0.f, 0.f, 0.f, 0.f};

  for (int kk = 0; kk < 16; ++kk) {
    const int k0 = kk * 32;
    {  // stage A: 64 x 32 fp32 -> bf16
      int row = t >> 2, cq = t & 3;
      const float4* src = reinterpret_cast<const float4*>(
          x + (size_t)(m0 + row) * 512 + k0 + cq * 8);
      float4 f0 = src[0], f1 = src[1];
      u16x8 h;
      h[0] = f2bf(f0.x); h[1] = f2bf(f0.y); h[2] = f2bf(f0.z); h[3] = f2bf(f0.w);
      h[4] = f2bf(f1.x); h[5] = f2bf(f1.y); h[6] = f2bf(f1.z); h[7] = f2bf(f1.w);
      *reinterpret_cast<u16x8*>(&As[row][cq * 8]) = h;
    }
    {  // stage B: 128 x 32 bf16
      int row = t >> 1, hh = t & 1;
      const uint4* src = reinterpret_cast<const uint4*>(
          W1 + (size_t)row * 512 + k0 + hh * 16);
      uint4 d0 = src[0], d1 = src[1];
      *reinterpret_cast<uint4*>(&Bs[row][hh * 16]) = d0;
      *reinterpret_cast<uint4*>(&Bs[row][hh * 16 + 8]) = d1;
    }
    __syncthreads();
    bf16x8 af = frag_at(&As[w * 16 + lr][lg * 8]);
#pragma unroll
    for (int cb = 0; cb < 8; ++cb) {
      bf16x8 bfr = frag_at(&Bs[cb * 16 + lr][lg * 8]);
      acc[cb] = mfma16(af, bfr, acc[cb]);
    }
    __syncthreads();
  }
#pragma unroll
  for (int cb = 0; cb < 8; ++cb) {
    int o = cb * 16 + lr;
    float bias = b1[o];
#pragma unroll
    for (int i = 0; i < 4; ++i) {
      int token = m0 + w * 16 + lg * 4 + i;
      unsigned short hv = f2bf(acc[cb][i] + bias);
      if (o < 64) kbf[(size_t)token * 64 + o] = hv;
      else        vtbf[(size_t)token * 64 + (o - 64)] = hv;
    }
  }
}

// ---------------- P2: qt[b, c, n] = (Wq @ x[b]^T + bq)  ------------------
// per b: M=512 (o), N=2048 (n), K=512 (c). A=Wq rows, B=x rows (n-major).
__global__ __launch_bounds__(256) void proj_q_kernel(
    const float* __restrict__ x, const unsigned short* __restrict__ Wqb,
    const float* __restrict__ bq, unsigned short* __restrict__ qt) {
  __shared__ unsigned short As[64][40];   // [o][k]
  __shared__ unsigned short Bs[128][40];  // [n][k]
  const int t = threadIdx.x;
  const int bi = blockIdx.x;
  const int b = bi >> 7, rem = bi & 127, ot = rem >> 4, nt = rem & 15;
  const int o0 = ot * 64, n0 = nt * 128;
  const int w = t >> 6, lane = t & 63, lr = lane & 15, lg = lane >> 4;
  f32x4 acc[8];
#pragma unroll
  for (int i = 0; i < 8; ++i) acc[i] = (f32x4){0.f, 0.f, 0.f, 0.f};

  for (int kk = 0; kk < 16; ++kk) {
    const int k0 = kk * 32;
    {  // stage A: Wq 64 x 32 bf16
      int row = t >> 2, cq = t & 3;
      uint4 d = *reinterpret_cast<const uint4*>(
          Wqb + (size_t)(o0 + row) * 512 + k0 + cq * 8);
      *reinterpret_cast<uint4*>(&As[row][cq * 8]) = d;
    }
    {  // stage B: x 128 x 32 fp32 -> bf16
      int row = t >> 1, hh = t & 1;
      const float4* src = reinterpret_cast<const float4*>(
          x + ((size_t)b * 2048 + n0 + row) * 512 + k0 + hh * 16);
      float4 f0 = src[0], f1 = src[1], f2 = src[2], f3 = src[3];
      u16x8 h0, h1;
      h0[0] = f2bf(f0.x); h0[1] = f2bf(f0.y); h0[2] = f2bf(f0.z); h0[3] = f2bf(f0.w);
      h0[4] = f2bf(f1.x); h0[5] = f2bf(f1.y); h0[6] = f2bf(f1.z); h0[7] = f2bf(f1.w);
      h1[0] = f2bf(f2.x); h1[1] = f2bf(f2.y); h1[2] = f2bf(f2.z); h1[3] = f2bf(f2.w);
      h1[4] = f2bf(f3.x); h1[5] = f2bf(f3.y); h1[6] = f2bf(f3.z); h1[7] = f2bf(f3.w);
      *reinterpret_cast<u16x8*>(&Bs[row][hh * 16]) = h0;
      *reinterpret_cast<u16x8*>(&Bs[row][hh * 16 + 8]) = h1;
    }
    __syncthreads();
    bf16x8 af = frag_at(&As[w * 16 + lr][lg * 8]);
#pragma unroll
    for (int cb = 0; cb < 8; ++cb) {
      bf16x8 bfr = frag_at(&Bs[cb * 16 + lr][lg * 8]);
      acc[cb] = mfma16(af, bfr, acc[cb]);
    }
    __syncthreads();
  }
#pragma unroll
  for (int i = 0; i < 4; ++i) {
    int o = o0 + w * 16 + lg * 4 + i;
    float bias = bq[o];
#pragma unroll
    for (int cb = 0; cb < 8; ++cb) {
      int n = n0 + cb * 16 + lr;
      qt[((size_t)b * 512 + o) * 2048 + n] = f2bf(acc[cb][i] + bias);
    }
  }
}

// ---------------- attention: out = gamma * softmax-combine + x ------------
// block: (b, m-tile of 64). 4 waves x 16 rows. NTILE=64 keys per iter.
__global__ __launch_bounds__(256, 1) void attn_kernel(
    const float* __restrict__ x, const unsigned short* __restrict__ kbf,
    const unsigned short* __restrict__ vtbf, const unsigned short* __restrict__ qt,
    const float* __restrict__ g, float* __restrict__ out) {
  __shared__ unsigned short k_lds[64][72];    // [n][o]   9216 B
  __shared__ unsigned short qt_lds[512][72];  // [c][n]  73728 B
  __shared__ unsigned short p_lds[4][16][72]; // per-wave P tile
  const int t = threadIdx.x;
  const int b = blockIdx.x & 7, mt = blockIdx.x >> 3;
  const int m0 = mt * 64;
  const int w = t >> 6, lane = t & 63, lr = lane & 15, lg = lane >> 4;

  // A-fragments for S: vt rows (this wave's 16 m-rows), K=64 -> 2 frags
  bf16x8 qf[2];
#pragma unroll
  for (int s = 0; s < 2; ++s)
    qf[s] = frag_at(vtbf + ((size_t)(b * 2048 + m0 + w * 16 + lr)) * 64 + s * 32 + lg * 8);

  f32x4 acc[32];
#pragma unroll
  for (int i = 0; i < 32; ++i) acc[i] = (f32x4){0.f, 0.f, 0.f, 0.f};
  float dsum[4] = {0.f, 0.f, 0.f, 0.f};

  for (int nt = 0; nt < 32; ++nt) {
    const int n0 = nt * 64;
    {  // stage k tile [64 n][64 o]
      int row = t >> 2, cq = t & 3;
      const uint4* src = reinterpret_cast<const uint4*>(
          kbf + ((size_t)(b * 2048 + n0 + row)) * 64 + cq * 8);
      uint4 d0 = src[0], d1 = src[4];
      *reinterpret_cast<uint4*>(&k_lds[row][cq * 8]) = d0;
      *reinterpret_cast<uint4*>(&k_lds[row][cq * 8 + 32]) = d1;
    }
    {  // stage qt tile [512 c][64 n]
      int cq = t & 3, rbase = t >> 2;
#pragma unroll
      for (int pass = 0; pass < 8; ++pass) {
        int c = pass * 64 + rbase;
        const uint4* src = reinterpret_cast<const uint4*>(
            qt + ((size_t)(b * 512 + c)) * 2048 + n0 + cq * 8);
        uint4 d0 = src[0], d1 = src[4];
        *reinterpret_cast<uint4*>(&qt_lds[c][cq * 8]) = d0;
        *reinterpret_cast<uint4*>(&qt_lds[c][cq * 8 + 32]) = d1;
      }
    }
    __syncthreads();

    // S = vt . k^T   (S[m16][n64])
    f32x4 sacc[4];
#pragma unroll
    for (int nb = 0; nb < 4; ++nb) sacc[nb] = (f32x4){0.f, 0.f, 0.f, 0.f};
#pragma unroll
    for (int nb = 0; nb < 4; ++nb) {
#pragma unroll
      for (int s = 0; s < 2; ++s) {
        bf16x8 kf = frag_at(&k_lds[nb * 16 + lr][s * 32 + lg * 8]);
        sacc[nb] = mfma16(qf[s], kf, sacc[nb]);
      }
    }
    // P = exp(S); accumulate denominator; write P to LDS (D-layout -> A-layout)
#pragma unroll
    for (int nb = 0; nb < 4; ++nb) {
#pragma unroll
      for (int i = 0; i < 4; ++i) {
        float e = __expf(sacc[nb][i]);
        dsum[i] += e;
        p_lds[w][lg * 4 + i][nb * 16 + lr] = f2bf(e);
      }
    }
    __syncthreads();  // p_lds visibility (also keeps waves loosely in step)

    bf16x8 pf[2];
#pragma unroll
    for (int s = 0; s < 2; ++s)
      pf[s] = frag_at(&p_lds[w][lr][s * 32 + lg * 8]);

    // PV: acc[m16][c512] += P . qt-tile
#pragma unroll
    for (int cb = 0; cb < 32; ++cb) {
#pragma unroll
      for (int s = 0; s < 2; ++s) {
        bf16x8 vf = frag_at(&qt_lds[cb * 16 + lr][s * 32 + lg * 8]);
        acc[cb] = mfma16(pf[s], vf, acc[cb]);
      }
    }
    __syncthreads();  // before next tile's staging overwrites LDS
  }

  // reduce denominator across the 16 column-lanes of each row group
#pragma unroll
  for (int i = 0; i < 4; ++i) {
    float d = dsum[i];
    d += __shfl_xor(d, 1);
    d += __shfl_xor(d, 2);
    d += __shfl_xor(d, 4);
    d += __shfl_xor(d, 8);
    dsum[i] = d;
  }
  const float gamma = g[0];
#pragma unroll
  for (int i = 0; i < 4; ++i) {
    int m = m0 + w * 16 + lg * 4 + i;
    float inv = 1.0f / dsum[i];
    size_t base = ((size_t)b * 2048 + m) * 512;
#pragma unroll
    for (int cb = 0; cb < 32; ++cb) {
      int c = cb * 16 + lr;
      float r = acc[cb][i] * inv;
      out[base + c] = gamma * r + x[base + c];
    }
  }
}

// ---------------- launcher ----------------
extern "C" void kernel_launch(void* const* d_in, const int* in_sizes, int n_in,
                              void* d_out, int out_size, void* d_ws, size_t ws_size,
                              hipStream_t stream) {
  const float* x  = (const float*)d_in[0];
  const float* Wk = (const float*)d_in[1];
  const float* bk = (const float*)d_in[2];
  const float* Wv = (const float*)d_in[3];
  const float* bv = (const float*)d_in[4];
  const float* Wq = (const float*)d_in[5];
  const float* bq = (const float*)d_in[6];
  const float* g  = (const float*)d_in[7];
  float* out = (float*)d_out;

  char* ws = (char*)d_ws;
  const size_t OFF_W1  = 0;                      // 128*512*2   = 131072
  const size_t OFF_WQ  = OFF_W1 + 131072;        // 512*512*2   = 524288
  const size_t OFF_B1  = OFF_WQ + 524288;        // 128*4       = 512
  const size_t OFF_K   = 656384;                 // 16384*64*2  = 2097152
  const size_t OFF_VT  = OFF_K + 2097152;
  const size_t OFF_QT  = OFF_VT + 2097152;       // 8*512*2048*2 = 16777216 (ends ~21.6 MB)
  unsigned short* W1   = (unsigned short*)(ws + OFF_W1);
  unsigned short* Wqb  = (unsigned short*)(ws + OFF_WQ);
  float*          b1   = (float*)(ws + OFF_B1);
  unsigned short* kbf  = (unsigned short*)(ws + OFF_K);
  unsigned short* vtbf = (unsigned short*)(ws + OFF_VT);
  unsigned short* qt   = (unsigned short*)(ws + OFF_QT);

  hipLaunchKernelGGL(prep_kernel, dim3(256), dim3(256), 0, stream,
                     Wk, bk, Wv, bv, Wq, W1, b1, Wqb);
  hipLaunchKernelGGL(proj_kv_kernel, dim3(256), dim3(256), 0, stream,
                     x, W1, b1, kbf, vtbf);
  hipLaunchKernelGGL(proj_q_kernel, dim3(1024), dim3(256), 0, stream,
                     x, Wqb, bq, qt);
  hipLaunchKernelGGL(attn_kernel, dim3(256), dim3(256), 0, stream,
                     x, kbf, vtbf, qt, g, out);
}

// Round 2
// 226.691 us; speedup vs baseline: 1.3778x; 1.3778x over previous
//
#include <hip/hip_runtime.h>

// Problem constants: B=8, N=2048, C=512, CR=64
#define PB 8
#define PN 2048
#define PC 512

typedef __attribute__((ext_vector_type(4))) float f32x4;
typedef __attribute__((ext_vector_type(8))) __bf16 bf16x8;
typedef __attribute__((ext_vector_type(8))) unsigned short u16x8;

__device__ __forceinline__ unsigned short f2bf(float f) {
  unsigned u = __builtin_bit_cast(unsigned, f);
  u += 0x7fffu + ((u >> 16) & 1u);
  return (unsigned short)(u >> 16);
}

__device__ __forceinline__ bf16x8 frag_at(const unsigned short* p) {
  return *reinterpret_cast<const bf16x8*>(p);
}

__device__ __forceinline__ f32x4 mfma16(bf16x8 a, bf16x8 b, f32x4 c) {
  return __builtin_amdgcn_mfma_f32_16x16x32_bf16(a, b, c, 0, 0, 0);
}

// ---------------- prep: cast weights to bf16, concat Wk/Wv ----------------
__global__ void prep_kernel(const float* __restrict__ Wk, const float* __restrict__ bk,
                            const float* __restrict__ Wv, const float* __restrict__ bv,
                            const float* __restrict__ Wq,
                            unsigned short* __restrict__ W1, float* __restrict__ b1,
                            unsigned short* __restrict__ Wqb) {
  int i = blockIdx.x * blockDim.x + threadIdx.x;
  int stride = gridDim.x * blockDim.x;
  for (int t = i; t < 128 * 512; t += stride) {
    int o = t >> 9, c = t & 511;
    float v = (o < 64) ? Wk[o * 512 + c] : Wv[(o - 64) * 512 + c];
    W1[t] = f2bf(v);
  }
  for (int t = i; t < 512 * 512; t += stride) Wqb[t] = f2bf(Wq[t]);
  if (i < 64) b1[i] = bk[i];
  else if (i < 128) b1[i] = bv[i - 64];
}

// ---------------- P1: k[b,n,64], vt[b,n,64] = x @ [Wk;Wv]^T + bias --------
__global__ __launch_bounds__(256) void proj_kv_kernel(
    const float* __restrict__ x, const unsigned short* __restrict__ W1,
    const float* __restrict__ b1,
    unsigned short* __restrict__ kbf, unsigned short* __restrict__ vtbf) {
  __shared__ unsigned short As[64][40];   // [token][k]  (+8 pad)
  __shared__ unsigned short Bs[128][40];  // [o][k]
  const int t = threadIdx.x;
  const int m0 = blockIdx.x * 64;
  const int w = t >> 6, lane = t & 63, lr = lane & 15, lg = lane >> 4;
  f32x4 acc[8];
#pragma unroll
  for (int i = 0; i < 8; ++i) acc[i] = (f32x4){0.f, 0.f, 0.f, 0.f};

  for (int kk = 0; kk < 16; ++kk) {
    const int k0 = kk * 32;
    {  // stage A: 64 x 32 fp32 -> bf16
      int row = t >> 2, cq = t & 3;
      const float4* src = reinterpret_cast<const float4*>(
          x + (size_t)(m0 + row) * 512 + k0 + cq * 8);
      float4 f0 = src[0], f1 = src[1];
      u16x8 h;
      h[0] = f2bf(f0.x); h[1] = f2bf(f0.y); h[2] = f2bf(f0.z); h[3] = f2bf(f0.w);
      h[4] = f2bf(f1.x); h[5] = f2bf(f1.y); h[6] = f2bf(f1.z); h[7] = f2bf(f1.w);
      *reinterpret_cast<u16x8*>(&As[row][cq * 8]) = h;
    }
    {  // stage B: 128 x 32 bf16
      int row = t >> 1, hh = t & 1;
      const uint4* src = reinterpret_cast<const uint4*>(
          W1 + (size_t)row * 512 + k0 + hh * 16);
      uint4 d0 = src[0], d1 = src[1];
      *reinterpret_cast<uint4*>(&Bs[row][hh * 16]) = d0;
      *reinterpret_cast<uint4*>(&Bs[row][hh * 16 + 8]) = d1;
    }
    __syncthreads();
    bf16x8 af = frag_at(&As[w * 16 + lr][lg * 8]);
#pragma unroll
    for (int cb = 0; cb < 8; ++cb) {
      bf16x8 bfr = frag_at(&Bs[cb * 16 + lr][lg * 8]);
      acc[cb] = mfma16(af, bfr, acc[cb]);
    }
    __syncthreads();
  }
#pragma unroll
  for (int cb = 0; cb < 8; ++cb) {
    int o = cb * 16 + lr;
    float bias = b1[o];
#pragma unroll
    for (int i = 0; i < 4; ++i) {
      int token = m0 + w * 16 + lg * 4 + i;
      unsigned short hv = f2bf(acc[cb][i] + bias);
      if (o < 64) kbf[(size_t)token * 64 + o] = hv;
      else        vtbf[(size_t)token * 64 + (o - 64)] = hv;
    }
  }
}

// ---------------- P2: qt[b, c, n] = (Wq @ x[b]^T + bq)  ------------------
__global__ __launch_bounds__(256) void proj_q_kernel(
    const float* __restrict__ x, const unsigned short* __restrict__ Wqb,
    const float* __restrict__ bq, unsigned short* __restrict__ qt) {
  __shared__ unsigned short As[64][40];   // [o][k]
  __shared__ unsigned short Bs[128][40];  // [n][k]
  const int t = threadIdx.x;
  const int bi = blockIdx.x;
  const int b = bi >> 7, rem = bi & 127, ot = rem >> 4, nt = rem & 15;
  const int o0 = ot * 64, n0 = nt * 128;
  const int w = t >> 6, lane = t & 63, lr = lane & 15, lg = lane >> 4;
  f32x4 acc[8];
#pragma unroll
  for (int i = 0; i < 8; ++i) acc[i] = (f32x4){0.f, 0.f, 0.f, 0.f};

  for (int kk = 0; kk < 16; ++kk) {
    const int k0 = kk * 32;
    {  // stage A: Wq 64 x 32 bf16
      int row = t >> 2, cq = t & 3;
      uint4 d = *reinterpret_cast<const uint4*>(
          Wqb + (size_t)(o0 + row) * 512 + k0 + cq * 8);
      *reinterpret_cast<uint4*>(&As[row][cq * 8]) = d;
    }
    {  // stage B: x 128 x 32 fp32 -> bf16
      int row = t >> 1, hh = t & 1;
      const float4* src = reinterpret_cast<const float4*>(
          x + ((size_t)b * 2048 + n0 + row) * 512 + k0 + hh * 16);
      float4 f0 = src[0], f1 = src[1], f2 = src[2], f3 = src[3];
      u16x8 h0, h1;
      h0[0] = f2bf(f0.x); h0[1] = f2bf(f0.y); h0[2] = f2bf(f0.z); h0[3] = f2bf(f0.w);
      h0[4] = f2bf(f1.x); h0[5] = f2bf(f1.y); h0[6] = f2bf(f1.z); h0[7] = f2bf(f1.w);
      h1[0] = f2bf(f2.x); h1[1] = f2bf(f2.y); h1[2] = f2bf(f2.z); h1[3] = f2bf(f2.w);
      h1[4] = f2bf(f3.x); h1[5] = f2bf(f3.y); h1[6] = f2bf(f3.z); h1[7] = f2bf(f3.w);
      *reinterpret_cast<u16x8*>(&Bs[row][hh * 16]) = h0;
      *reinterpret_cast<u16x8*>(&Bs[row][hh * 16 + 8]) = h1;
    }
    __syncthreads();
    bf16x8 af = frag_at(&As[w * 16 + lr][lg * 8]);
#pragma unroll
    for (int cb = 0; cb < 8; ++cb) {
      bf16x8 bfr = frag_at(&Bs[cb * 16 + lr][lg * 8]);
      acc[cb] = mfma16(af, bfr, acc[cb]);
    }
    __syncthreads();
  }
#pragma unroll
  for (int i = 0; i < 4; ++i) {
    int o = o0 + w * 16 + lg * 4 + i;
    float bias = bq[o];
#pragma unroll
    for (int cb = 0; cb < 8; ++cb) {
      int n = n0 + cb * 16 + lr;
      qt[((size_t)b * 512 + o) * 2048 + n] = f2bf(acc[cb][i] + bias);
    }
  }
}

// ---------------- attention ------------------------------------------------
// Block: (b = blockIdx&7 -> XCD-local, m-tile of 64). 512 threads = 8 waves.
// PV c-split: wave w owns c in [w*64, w*64+64) for ALL 64 m rows
//   -> each qt element read by exactly ONE wave -> read B-frags straight
//      from global (L2-resident, 2MB/batch/XCD); no qt LDS staging.
// S m/n-split: wave w computes S[16m x 32n] (mcS = w>>1, nh = w&1),
//   k B-frags also straight from global (L1 absorbs 4-way wave duplication).
// Only P goes through LDS (D-frag -> A-frag layout fix), double-buffered
//   -> ONE barrier per n-tile.
__global__ __launch_bounds__(512, 1) void attn_kernel(
    const float* __restrict__ x, const unsigned short* __restrict__ kbf,
    const unsigned short* __restrict__ vtbf, const unsigned short* __restrict__ qt,
    const float* __restrict__ g, float* __restrict__ out) {
  __shared__ unsigned short p_lds[2][64][72];  // 2 x 9.2 KB
  __shared__ float dsum_lds[2][64];
  const int t = threadIdx.x;
  const int b = blockIdx.x & 7, mt = blockIdx.x >> 3;
  const int m0 = mt * 64;
  const int w = t >> 6, lane = t & 63, lr = lane & 15, lg = lane >> 4;
  const int mcS = w >> 1, nh = w & 1;   // S-phase tile assignment
  const int cbase = w * 64;             // PV c-range start

  // A-frags for S: vt rows of this wave's 16 m-rows (K=64 -> 2 frags)
  bf16x8 qf[2];
  const unsigned short* vrow =
      vtbf + ((size_t)(b * 2048 + m0 + mcS * 16 + lr)) * 64;
  qf[0] = frag_at(vrow + lg * 8);
  qf[1] = frag_at(vrow + 32 + lg * 8);

  f32x4 acc[4][4];  // [mc][cb] : 64 m x 64 c per wave
#pragma unroll
  for (int mc = 0; mc < 4; ++mc)
#pragma unroll
    for (int cb = 0; cb < 4; ++cb) acc[mc][cb] = (f32x4){0.f, 0.f, 0.f, 0.f};
  float dsum[4] = {0.f, 0.f, 0.f, 0.f};

  const unsigned short* kbase = kbf + (size_t)b * 2048 * 64;
  const unsigned short* qtb   = qt + (size_t)b * 512 * 2048;

  for (int nt = 0; nt < 32; ++nt) {
    const int n0 = nt * 64;
    const int buf = nt & 1;

    // Issue PV B-frag loads early (independent of P) so L2 latency hides
    // under S + exp + barrier.
    bf16x8 bfr[4][2];
#pragma unroll
    for (int cb = 0; cb < 4; ++cb) {
      const unsigned short* qrow =
          qtb + (size_t)(cbase + cb * 16 + lr) * 2048 + n0;
      bfr[cb][0] = frag_at(qrow + lg * 8);
      bfr[cb][1] = frag_at(qrow + 32 + lg * 8);
    }

    // S = vt . k^T for this wave's [16m x 32n] quarter
    f32x4 sacc[2];
    sacc[0] = (f32x4){0.f, 0.f, 0.f, 0.f};
    sacc[1] = (f32x4){0.f, 0.f, 0.f, 0.f};
#pragma unroll
    for (int nb = 0; nb < 2; ++nb) {
      const unsigned short* krow =
          kbase + (size_t)(n0 + nh * 32 + nb * 16 + lr) * 64;
#pragma unroll
      for (int s = 0; s < 2; ++s) {
        bf16x8 kf = frag_at(krow + s * 32 + lg * 8);
        sacc[nb] = mfma16(qf[s], kf, sacc[nb]);
      }
    }

    // P = exp(S); accumulate denominator; write P (A-frag layout)
#pragma unroll
    for (int nb = 0; nb < 2; ++nb)
#pragma unroll
      for (int i = 0; i < 4; ++i) {
        float e = __expf(sacc[nb][i]);
        dsum[i] += e;
        p_lds[buf][mcS * 16 + lg * 4 + i][nh * 32 + nb * 16 + lr] = f2bf(e);
      }
    __syncthreads();  // the only barrier per tile (P double-buffered)

    // PV: acc[64m x 64c] += P . qt
#pragma unroll
    for (int mc = 0; mc < 4; ++mc) {
      bf16x8 pf0 = frag_at(&p_lds[buf][mc * 16 + lr][lg * 8]);
      bf16x8 pf1 = frag_at(&p_lds[buf][mc * 16 + lr][32 + lg * 8]);
#pragma unroll
      for (int cb = 0; cb < 4; ++cb) {
        acc[mc][cb] = mfma16(pf0, bfr[cb][0], acc[mc][cb]);
        acc[mc][cb] = mfma16(pf1, bfr[cb][1], acc[mc][cb]);
      }
    }
  }

  // Denominator: reduce this wave's 32n partial across 16 column-lanes,
  // then combine the two n-halves via LDS.
#pragma unroll
  for (int i = 0; i < 4; ++i) {
    float d = dsum[i];
    d += __shfl_xor(d, 1);
    d += __shfl_xor(d, 2);
    d += __shfl_xor(d, 4);
    d += __shfl_xor(d, 8);
    dsum[i] = d;
  }
  if (lr == 0) {
#pragma unroll
    for (int i = 0; i < 4; ++i)
      dsum_lds[nh][mcS * 16 + lg * 4 + i] = dsum[i];
  }
  __syncthreads();

  const float gamma = g[0];
#pragma unroll
  for (int mc = 0; mc < 4; ++mc) {
#pragma unroll
    for (int i = 0; i < 4; ++i) {
      int mrow = mc * 16 + lg * 4 + i;
      float inv = 1.0f / (dsum_lds[0][mrow] + dsum_lds[1][mrow]);
      size_t base = ((size_t)b * 2048 + (m0 + mrow)) * 512 + cbase;
#pragma unroll
      for (int cb = 0; cb < 4; ++cb) {
        int c = cb * 16 + lr;
        out[base + c] = gamma * (acc[mc][cb][i] * inv) + x[base + c];
      }
    }
  }
}

// ---------------- launcher ----------------
extern "C" void kernel_launch(void* const* d_in, const int* in_sizes, int n_in,
                              void* d_out, int out_size, void* d_ws, size_t ws_size,
                              hipStream_t stream) {
  const float* x  = (const float*)d_in[0];
  const float* Wk = (const float*)d_in[1];
  const float* bk = (const float*)d_in[2];
  const float* Wv = (const float*)d_in[3];
  const float* bv = (const float*)d_in[4];
  const float* Wq = (const float*)d_in[5];
  const float* bq = (const float*)d_in[6];
  const float* g  = (const float*)d_in[7];
  float* out = (float*)d_out;

  char* ws = (char*)d_ws;
  const size_t OFF_W1  = 0;                      // 128*512*2   = 131072
  const size_t OFF_WQ  = OFF_W1 + 131072;        // 512*512*2   = 524288
  const size_t OFF_B1  = OFF_WQ + 524288;        // 128*4       = 512
  const size_t OFF_K   = 656384;                 // 16384*64*2  = 2097152
  const size_t OFF_VT  = OFF_K + 2097152;
  const size_t OFF_QT  = OFF_VT + 2097152;       // 8*512*2048*2 = 16777216
  unsigned short* W1   = (unsigned short*)(ws + OFF_W1);
  unsigned short* Wqb  = (unsigned short*)(ws + OFF_WQ);
  float*          b1   = (float*)(ws + OFF_B1);
  unsigned short* kbf  = (unsigned short*)(ws + OFF_K);
  unsigned short* vtbf = (unsigned short*)(ws + OFF_VT);
  unsigned short* qt   = (unsigned short*)(ws + OFF_QT);

  hipLaunchKernelGGL(prep_kernel, dim3(256), dim3(256), 0, stream,
                     Wk, bk, Wv, bv, Wq, W1, b1, Wqb);
  hipLaunchKernelGGL(proj_kv_kernel, dim3(256), dim3(256), 0, stream,
                     x, W1, b1, kbf, vtbf);
  hipLaunchKernelGGL(proj_q_kernel, dim3(1024), dim3(256), 0, stream,
                     x, Wqb, bq, qt);
  hipLaunchKernelGGL(attn_kernel, dim3(256), dim3(512), 0, stream,
                     x, kbf, vtbf, qt, g, out);
}